// Round 1
// baseline (401.860 us; speedup 1.0000x reference)
//
#include <hip/hip_runtime.h>

// Problem constants (from reference)
#define BB 4
#define CC 256
#define HH 256
#define WW 256
#define N_BOX 64
#define SS 7
#define NPTS (SS * SS)        // 49
#define NROI (BB * N_BOX)     // 256
#define CG 64                 // channels per block
#define NG (CC / CG)          // 4 channel groups
#define ITEMS (CG * NPTS)     // 3136 output elements per block
#define ROI_SCALE 0.25f

__global__ __launch_bounds__(256) void rotated_roi_align_kernel(
    const float* __restrict__ feats,   // (B, C, H, W)
    const float* __restrict__ rois,    // (B, N_BOX, 5): cx, cy, w, h, theta (world coords)
    float* __restrict__ out)           // (B*N_BOX, C, S, S)
{
    __shared__ int   s_off[4][NPTS];   // clamped flat offsets y*W+x per corner
    __shared__ float s_w[4][NPTS];     // bilinear weight * validity per corner

    const int r   = blockIdx.x;        // roi index 0..255
    const int cq  = blockIdx.y;        // channel group 0..NG-1
    const int b   = r >> 6;            // r / N_BOX
    const int tid = threadIdx.x;

    // ---- Per-point precompute (threads 0..48) ----
    if (tid < NPTS) {
        const float cx = rois[r * 5 + 0] * ROI_SCALE;
        const float cy = rois[r * 5 + 1] * ROI_SCALE;
        const float bw = rois[r * 5 + 2] * ROI_SCALE;
        const float bh = rois[r * 5 + 3] * ROI_SCALE;
        const float th = rois[r * 5 + 4];
        const float ct = cosf(th);
        const float st = sinf(th);

        const int py = tid / SS;
        const int px = tid - py * SS;
        // lin = (k + 0.5)/S - 0.5
        const float lu = (px + 0.5f) / (float)SS - 0.5f;
        const float lv = (py + 0.5f) / (float)SS - 0.5f;
        const float u = lu * bw;
        const float v = lv * bh;
        const float x = cx + u * ct - v * st;
        const float y = cy + u * st + v * ct;

        const float x0f = floorf(x), y0f = floorf(y);
        const float x1f = x0f + 1.0f, y1f = y0f + 1.0f;
        const float wx1 = x - x0f, wx0 = 1.0f - wx1;
        const float wy1 = y - y0f, wy0 = 1.0f - wy1;

        const bool vx0 = (x0f >= 0.0f) && (x0f <= (float)(WW - 1));
        const bool vx1 = (x1f >= 0.0f) && (x1f <= (float)(WW - 1));
        const bool vy0 = (y0f >= 0.0f) && (y0f <= (float)(HH - 1));
        const bool vy1 = (y1f >= 0.0f) && (y1f <= (float)(HH - 1));

        const int x0c = min(max((int)x0f, 0), WW - 1);
        const int x1c = min(max((int)x1f, 0), WW - 1);
        const int y0c = min(max((int)y0f, 0), HH - 1);
        const int y1c = min(max((int)y1f, 0), HH - 1);

        s_off[0][tid] = y0c * WW + x0c;  s_w[0][tid] = (vx0 && vy0) ? wx0 * wy0 : 0.0f;
        s_off[1][tid] = y0c * WW + x1c;  s_w[1][tid] = (vx1 && vy0) ? wx1 * wy0 : 0.0f;
        s_off[2][tid] = y1c * WW + x0c;  s_w[2][tid] = (vx0 && vy1) ? wx0 * wy1 : 0.0f;
        s_off[3][tid] = y1c * WW + x1c;  s_w[3][tid] = (vx1 && vy1) ? wx1 * wy1 : 0.0f;
    }
    __syncthreads();

    // ---- Gather + coalesced write ----
    // Output for this block is the contiguous range
    //   out[r*C*49 + cq*CG*49 .. +ITEMS), laid out as (c_local, p) row-major —
    // identical to the loop index i, so stores are fully coalesced.
    const float* plane_base = feats + ((size_t)b * CC + (size_t)cq * CG) * (HH * WW);
    float* ob = out + (size_t)r * CC * NPTS + (size_t)cq * CG * NPTS;

    #pragma unroll 4
    for (int i = tid; i < ITEMS; i += 256) {
        const int cl = i / NPTS;          // local channel 0..CG-1
        const int p  = i - cl * NPTS;     // point 0..48
        const float* plane = plane_base + (size_t)cl * (HH * WW);
        const float v0 = plane[s_off[0][p]];
        const float v1 = plane[s_off[1][p]];
        const float v2 = plane[s_off[2][p]];
        const float v3 = plane[s_off[3][p]];
        ob[i] = s_w[0][p] * v0 + s_w[1][p] * v1 + s_w[2][p] * v2 + s_w[3][p] * v3;
    }
}

extern "C" void kernel_launch(void* const* d_in, const int* in_sizes, int n_in,
                              void* d_out, int out_size, void* d_ws, size_t ws_size,
                              hipStream_t stream) {
    const float* feats = (const float*)d_in[0];
    const float* rois  = (const float*)d_in[1];
    float* out = (float*)d_out;

    dim3 grid(NROI, NG);   // 256 rois x 4 channel groups = 1024 blocks
    rotated_roi_align_kernel<<<grid, 256, 0, stream>>>(feats, rois, out);
}